// Round 7
// baseline (2588.746 us; speedup 1.0000x reference)
//
#include <hip/hip_runtime.h>
#include <stdint.h>

// N=64, T=128, D=512, H=1024, 4H=4096.
// R6: persistent kernel, ZERO flags. All cross-wg exchange is self-describing
// tagged 8-B atomics (3xbf16 + 16-bit step tag for h; f32 + 32-bit tag for w).
// Producer store -> consumer data-poll is the entire sync chain (1 MALL hop).
// Also: xwx pre-swizzled (exact-read), coalesced out stores, no memsets.
//   xwx2[(n*T+t)*128+C][32] = x@Wx + b   (swizzled for consumer wg C)
//   P2[n,col,l] = Af[n,:,l]@Wattn[:,col] (precomputed bf16 MFMA GEMM)

#define Tt 128
#define FH 4096

typedef __bf16 bf8 __attribute__((ext_vector_type(8)));
typedef float f4 __attribute__((ext_vector_type(4)));
typedef short s8v __attribute__((ext_vector_type(8)));
typedef unsigned long long ull;

__device__ __forceinline__ float bf2f(unsigned short u) {
    union { unsigned u32; float f; } x; x.u32 = ((unsigned)u) << 16; return x.f;
}
__device__ __forceinline__ unsigned short f2bf(float f) {
    union { float f32; unsigned u; } x; x.f32 = f;
    unsigned r = x.u + 0x7fffu + ((x.u >> 16) & 1u);
    return (unsigned short)(r >> 16);
}
__device__ __forceinline__ ull ald(const ull* p) {
    return __hip_atomic_load((ull*)p, __ATOMIC_RELAXED, __HIP_MEMORY_SCOPE_AGENT);
}
__device__ __forceinline__ void ast(ull* p, ull v) {
    __hip_atomic_store(p, v, __ATOMIC_RELAXED, __HIP_MEMORY_SCOPE_AGENT);
}

// ---------------- converts / init ----------------

__global__ __launch_bounds__(256) void k_cast_bf16(const float* __restrict__ in,
                                                   unsigned short* __restrict__ out, int n) {
    int i = blockIdx.x * 256 + threadIdx.x;
    if (i < n) out[i] = f2bf(in[i]);
}

__global__ __launch_bounds__(256) void k_transpose_bf16(const float* __restrict__ W,
                                                        unsigned short* __restrict__ WT, int K) {
    __shared__ float tl[32][33];
    int c0 = blockIdx.x * 32, k0 = blockIdx.y * 32;
    int tx = threadIdx.x & 31, ty = threadIdx.x >> 5;
    #pragma unroll
    for (int i = 0; i < 32; i += 8) tl[ty + i][tx] = W[(size_t)(k0 + ty + i) * 4096 + c0 + tx];
    __syncthreads();
    #pragma unroll
    for (int i = 0; i < 32; i += 8) WT[(size_t)(c0 + ty + i) * K + k0 + tx] = f2bf(tl[tx][ty + i]);
}

__global__ __launch_bounds__(256) void k_afl(const float* __restrict__ A,
                                             unsigned short* __restrict__ Afl) {
    int idx = blockIdx.x * 256 + threadIdx.x;
    int k = idx & 1023, l = (idx >> 10) & 15, n = idx >> 14;
    Afl[idx] = f2bf(A[((size_t)n * 1024 + k) * 16 + l]);
}

// h0 = mean over 16 locations; write cstate (fp32) + tagged Ht slot 0 (tag=0).
// 8192 threads: idx = n*128 + C2, each handles 8 h-cols [C2*8, C2*8+8).
__global__ __launch_bounds__(256) void k_init(const float* __restrict__ A,
                                              float* __restrict__ cstate,
                                              ull* __restrict__ Ht0) {
    int idx = blockIdx.x * 256 + threadIdx.x;
    int n = idx >> 7, C2 = idx & 127;
    unsigned short hb[8];
    #pragma unroll
    for (int jj = 0; jj < 8; jj++) {
        int j = C2 * 8 + jj;
        const float* ap = A + ((size_t)n * 1024 + j) * 16;
        float s = 0.f;
        #pragma unroll
        for (int l = 0; l < 16; l++) s += ap[l];
        float h = s * (1.0f / 16.0f);
        cstate[(size_t)n * 1024 + j] = h;
        hb[jj] = f2bf(h);
    }
    #pragma unroll
    for (int k = 0; k < 3; k++) {
        ull u = (ull)hb[k * 3];
        u |= (ull)hb[k * 3 + 1] << 16;
        if (k < 2) u |= (ull)hb[k * 3 + 2] << 32;
        // tag = 0 (high 16 bits zero)
        Ht0[(size_t)n * 384 + C2 * 3 + k] = u;   // plain store; kernel-end release
    }
}

// ---------------- generic bf16 MFMA GEMM (preamble) ----------------
// mode 0: out[row*Nn+col] ; mode 1: P2 layout ; mode 2: xwx2 swizzle
__global__ __launch_bounds__(256) void k_gemm(const unsigned short* __restrict__ A,
                                              const unsigned short* __restrict__ BT,
                                              const float* __restrict__ bias,
                                              unsigned short* __restrict__ out,
                                              int M, int Nn, int K, int mode) {
    __shared__ unsigned short As[128][40];
    __shared__ unsigned short Bs[128][40];
    int m0 = blockIdx.y * 128, n0 = blockIdx.x * 128;
    int tid = threadIdx.x, lane = tid & 63, wave = tid >> 6;
    int wr = wave >> 1, wc = wave & 1, quad = lane >> 4, l16 = lane & 15;
    f4 acc[4][4];
    #pragma unroll
    for (int i = 0; i < 4; i++)
        #pragma unroll
        for (int j = 0; j < 4; j++) acc[i][j] = f4{0.f, 0.f, 0.f, 0.f};

    for (int k0 = 0; k0 < K; k0 += 32) {
        __syncthreads();
        #pragma unroll
        for (int i = 0; i < 2; i++) {
            int idx = i * 256 + tid, r = idx >> 2, c = idx & 3;
            *(s8v*)&As[r][c * 8] = *(const s8v*)&A[(size_t)(m0 + r) * K + k0 + c * 8];
            *(s8v*)&Bs[r][c * 8] = *(const s8v*)&BT[(size_t)(n0 + r) * K + k0 + c * 8];
        }
        __syncthreads();
        bf8 af[4], bfr[4];
        #pragma unroll
        for (int i = 0; i < 4; i++) af[i] = *(const bf8*)&As[wr * 64 + i * 16 + l16][quad * 8];
        #pragma unroll
        for (int j = 0; j < 4; j++) bfr[j] = *(const bf8*)&Bs[wc * 64 + j * 16 + l16][quad * 8];
        #pragma unroll
        for (int i = 0; i < 4; i++)
            #pragma unroll
            for (int j = 0; j < 4; j++)
                acc[i][j] = __builtin_amdgcn_mfma_f32_16x16x32_bf16(af[i], bfr[j], acc[i][j], 0, 0, 0);
    }

    #pragma unroll
    for (int i = 0; i < 4; i++)
        #pragma unroll
        for (int j = 0; j < 4; j++) {
            int row0 = m0 + wr * 64 + i * 16 + quad * 4;
            int col = n0 + wc * 64 + j * 16 + l16;
            float bia = bias ? bias[col] : 0.0f;
            #pragma unroll
            for (int r = 0; r < 4; r++) {
                float v = acc[i][j][r] + bia;
                int rw = row0 + r;
                if (mode == 0) {
                    out[(size_t)rw * Nn + col] = f2bf(v);
                } else if (mode == 1) {
                    int n = rw >> 4, l = rw & 15;
                    out[((size_t)n * Nn + col) * 16 + l] = f2bf(v);
                } else {
                    int Cc = (col >> 3) & 127, g = col >> 10, jj = col & 7;
                    out[((size_t)rw * 128 + Cc) * 32 + g * 8 + jj] = f2bf(v);
                }
            }
        }
}

// ---------------- persistent recurrent kernel ----------------
// 256 gemm wgs (R=wid>>7 rows [32R,32R+32), C=wid&127 h-cols [8C,8C+8));
// 16 score wgs (wids 256..271, 1 row/wave). Grid 272, 2 wg/CU.
// Ht: 2 slots x 64 rows x 384 tagged ulls (chunk c: C2=c/3, k=c%3,
//     cols C2*8+k*3.. ; payload 3 (k<2) or 2 (k==2) bf16; tag = step).
// wbuf_t: 64 x 16 tagged ulls (low 32 = f32 w, high 32 = tag = t+1).
__global__ __launch_bounds__(256, 2) void k_recur(
    const float* __restrict__ Afull,
    const unsigned short* __restrict__ WhT,
    const unsigned short* __restrict__ xwx2,
    const unsigned short* __restrict__ P2,
    const float* __restrict__ cstate,
    ull* __restrict__ Ht, ull* __restrict__ wbuf_t,
    float* __restrict__ out) {
    __shared__ unsigned short hL[32][1032];  // 66 KB (+8 pad/row)
    __shared__ float aL[32][33];
    __shared__ float wL[512];
    __shared__ unsigned short hpk[32][8];
    __shared__ float hvL[32][8];

    const int wid = blockIdx.x;
    const int tid = threadIdx.x, lane = tid & 63, wave = tid >> 6;

    if (wid >= 256) {
        // ---------------- score wg: 4 rows, one per wave ----------------
        const int s = wid - 256;
        const int row = s * 4 + wave;
        const float* Ab = Afull + ((size_t)row * 1024 + lane * 16) * 16;
        for (int t = 0; t < Tt; ++t) {
            const ull* hb = Ht + (size_t)(t & 1) * 24576 + (size_t)row * 384 + lane * 6;
            ull c[6];
            unsigned pend = 0x3f;
            while (pend) {
                #pragma unroll
                for (int i = 0; i < 6; i++)
                    if (pend & (1u << i)) c[i] = ald(hb + i);
                unsigned np = 0;
                #pragma unroll
                for (int i = 0; i < 6; i++)
                    if ((pend & (1u << i)) && (unsigned)(c[i] >> 48) != (unsigned)t) np |= 1u << i;
                pend = np;
                if (pend) __builtin_amdgcn_s_sleep(1);
            }
            float hk[16];
            #pragma unroll
            for (int i = 0; i < 6; i++) {
                int base = (i / 3) * 8 + (i % 3) * 3;
                hk[base]     = bf2f((unsigned short)(c[i] & 0xffff));
                hk[base + 1] = bf2f((unsigned short)((c[i] >> 16) & 0xffff));
                if (i % 3 != 2) hk[base + 2] = bf2f((unsigned short)((c[i] >> 32) & 0xffff));
            }
            float part[16];
            #pragma unroll
            for (int l = 0; l < 16; l++) part[l] = 0.f;
            #pragma unroll
            for (int kk = 0; kk < 16; ++kk) {
                const f4* ar = (const f4*)(Ab + (size_t)kk * 16);
                f4 a0 = ar[0], a1 = ar[1], a2 = ar[2], a3 = ar[3];
                float hv = hk[kk];
                part[0]  += hv * a0.x;  part[1]  += hv * a0.y;
                part[2]  += hv * a0.z;  part[3]  += hv * a0.w;
                part[4]  += hv * a1.x;  part[5]  += hv * a1.y;
                part[6]  += hv * a1.z;  part[7]  += hv * a1.w;
                part[8]  += hv * a2.x;  part[9]  += hv * a2.y;
                part[10] += hv * a2.z;  part[11] += hv * a2.w;
                part[12] += hv * a3.x;  part[13] += hv * a3.y;
                part[14] += hv * a3.z;  part[15] += hv * a3.w;
            }
            #pragma unroll
            for (int l = 0; l < 16; l++) {
                float v = part[l];
                v += __shfl_down(v, 32, 64); v += __shfl_down(v, 16, 64);
                v += __shfl_down(v, 8, 64);  v += __shfl_down(v, 4, 64);
                v += __shfl_down(v, 2, 64);  v += __shfl_down(v, 1, 64);
                part[l] = v;
            }
            if (lane == 0) {
                float sc[16]; float mx = -1e30f;
                #pragma unroll
                for (int l = 0; l < 16; l++) {
                    sc[l] = part[l] * (1.0f / 32.0f);
                    mx = fmaxf(mx, sc[l]);
                }
                float sum = 0.f;
                #pragma unroll
                for (int l = 0; l < 16; l++) { sc[l] = __expf(sc[l] - mx); sum += sc[l]; }
                float inv = 1.0f / sum;
                #pragma unroll
                for (int l = 0; l < 16; l++) {
                    union { float f; unsigned u; } cv;
                    cv.f = sc[l] * inv;
                    ull u = (ull)cv.u | ((ull)(unsigned)(t + 1) << 32);
                    ast(wbuf_t + (size_t)row * 16 + l, u);
                }
            }
        }
        return;
    }

    // ---------------- gemm wg ----------------
    const int R = wid >> 7, C = wid & 127;
    const int quad = lane >> 4, l16 = lane & 15;
    const int rr = wave >> 1, cc = wave & 1;
    const int n_l = tid & 31, jl = tid >> 5;
    const int myn = R * 32 + n_l, myj = C * 8 + jl;
    const int cl = cc * 16 + l16;
    const int acol = ((cl >> 3) << 10) + C * 8 + (cl & 7);
    const size_t bbase = (size_t)acol * 1024 + quad * 8;

    float creg = cstate[(size_t)myn * 1024 + myj];   // c0 = h0, register-resident

    for (int t = 0; t < Tt; ++t) {
        // ---- prefetch epilogue operands (plain cached loads) ----
        unsigned short xw[4];
        s8v p0v[4], p1v[4];
        #pragma unroll
        for (int r = 0; r < 4; r++) {
            int nl = rr * 16 + quad * 4 + r;
            int n = R * 32 + nl;
            xw[r] = xwx2[((size_t)(n * Tt + t) * 128 + C) * 32 + cl];
            const unsigned short* pp = P2 + ((size_t)n * FH + acol) * 16;
            p0v[r] = *(const s8v*)pp;
            p1v[r] = *(const s8v*)(pp + 8);
        }

        // ---- stage h(t): wave handles rows [wave*8, wave*8+8), tagged poll ----
        const ull* hs = Ht + (size_t)(t & 1) * 24576 + (size_t)(R * 32) * 384;
        #pragma unroll
        for (int rg = 0; rg < 2; ++rg) {
            ull v[24];
            unsigned pend = 0xffffffu;
            while (pend) {
                #pragma unroll
                for (int ri = 0; ri < 4; ri++)
                    #pragma unroll
                    for (int it = 0; it < 6; it++) {
                        int b = ri * 6 + it;
                        if (pend & (1u << b))
                            v[b] = ald(hs + (size_t)(wave * 8 + rg * 4 + ri) * 384 + it * 64 + lane);
                    }
                unsigned np = 0;
                #pragma unroll
                for (int b = 0; b < 24; b++)
                    if ((pend & (1u << b)) && (unsigned)(v[b] >> 48) != (unsigned)t) np |= 1u << b;
                #pragma unroll
                for (int ri = 0; ri < 4; ri++)
                    #pragma unroll
                    for (int it = 0; it < 6; it++) {
                        int b = ri * 6 + it;
                        if ((pend & (1u << b)) && !(np & (1u << b))) {
                            int row = wave * 8 + rg * 4 + ri;
                            int cch = it * 64 + lane;
                            int C2 = cch / 3;
                            int k = cch - C2 * 3;
                            int col0 = C2 * 8 + k * 3;
                            ull val = v[b];
                            hL[row][col0]     = (unsigned short)val;
                            hL[row][col0 + 1] = (unsigned short)(val >> 16);
                            if (k < 2) hL[row][col0 + 2] = (unsigned short)(val >> 32);
                        }
                    }
                pend = np;
                if (pend) __builtin_amdgcn_s_sleep(1);
            }
        }
        __syncthreads();

        // ---- GEMM: h@Wh, A from LDS, B from L2 ----
        f4 acc = {0.f, 0.f, 0.f, 0.f};
        const unsigned short* hrow = &hL[rr * 16 + l16][quad * 8];
        #pragma unroll 8
        for (int ks = 0; ks < 32; ++ks) {
            bf8 a = *(const bf8*)(hrow + ks * 32);
            bf8 b = *(const bf8*)(WhT + bbase + ks * 32);
            acc = __builtin_amdgcn_mfma_f32_16x16x32_bf16(a, b, acc, 0, 0, 0);
        }

        // ---- softmax weights: tagged poll of 2 entries per thread ----
        {
            const size_t i0 = (size_t)R * 512 + tid * 2;
            ull w0 = ald(wbuf_t + i0);
            while ((unsigned)(w0 >> 32) != (unsigned)(t + 1)) {
                __builtin_amdgcn_s_sleep(1); w0 = ald(wbuf_t + i0);
            }
            ull w1 = ald(wbuf_t + i0 + 1);
            while ((unsigned)(w1 >> 32) != (unsigned)(t + 1)) {
                __builtin_amdgcn_s_sleep(1); w1 = ald(wbuf_t + i0 + 1);
            }
            union { unsigned u; float f; } cv0, cv1;
            cv0.u = (unsigned)w0; cv1.u = (unsigned)w1;
            wL[tid * 2] = cv0.f; wL[tid * 2 + 1] = cv1.f;
        }
        __syncthreads();

        // ---- epilogue: + xwx + attention (prefetched) -> aL ----
        #pragma unroll
        for (int r = 0; r < 4; r++) {
            int nl = rr * 16 + quad * 4 + r;
            float vv = acc[r] + bf2f(xw[r]);
            float ssum = 0.f;
            #pragma unroll
            for (int l = 0; l < 8; l++) ssum += wL[nl * 16 + l] * bf2f((unsigned short)p0v[r][l]);
            #pragma unroll
            for (int l = 0; l < 8; l++) ssum += wL[nl * 16 + 8 + l] * bf2f((unsigned short)p1v[r][l]);
            aL[nl][cl] = vv + ssum;
        }
        __syncthreads();

        // ---- gates (c register-resident) ----
        {
            float iv = aL[n_l][jl],      fv = aL[n_l][8 + jl];
            float ov = aL[n_l][16 + jl], gv = aL[n_l][24 + jl];
            float ig = 1.f / (1.f + __expf(-iv));
            float fg = 1.f / (1.f + __expf(-fv));
            float og = 1.f / (1.f + __expf(-ov));
            float gg = tanhf(gv);
            creg = fg * creg + ig * gg;
            float hv = og * tanhf(creg);
            hpk[n_l][jl] = f2bf(hv);
            hvL[n_l][jl] = hv;
        }
        __syncthreads();

        // ---- out write, coalesced 32B per 8 lanes ----
        {
            int row = tid >> 3, cj = tid & 7;
            out[((size_t)(R * 32 + row) * Tt + t) * 1024 + C * 8 + cj] = hvL[row][cj];
        }

        // ---- publish h(t+1): 96 tagged chunk stores (data IS the signal) ----
        if (t < Tt - 1 && tid < 96) {
            int n2 = tid / 3, k = tid - n2 * 3;
            ull u = (ull)hpk[n2][k * 3];
            u |= (ull)hpk[n2][k * 3 + 1] << 16;
            if (k < 2) u |= (ull)hpk[n2][k * 3 + 2] << 32;
            u |= (ull)(unsigned)(t + 1) << 48;
            ast(Ht + (size_t)((t + 1) & 1) * 24576 + (size_t)(R * 32 + n2) * 384 + C * 3 + k, u);
        }
    }
}

// ---------------- launch ----------------

extern "C" void kernel_launch(void* const* d_in, const int* in_sizes, int n_in,
                              void* d_out, int out_size, void* d_ws, size_t ws_size,
                              hipStream_t stream) {
    const float* x     = (const float*)d_in[0];   // [64][128][512]
    const float* A     = (const float*)d_in[1];   // [64][1024][16]
    const float* Wx    = (const float*)d_in[2];   // [512][4096]
    const float* Wh    = (const float*)d_in[3];   // [1024][4096]
    const float* Wattn = (const float*)d_in[4];   // [1024][4096]
    const float* b     = (const float*)d_in[5];   // [4096]
    float* out = (float*)d_out;
    char* ws = (char*)d_ws;

    unsigned short* xbf    = (unsigned short*)(ws);                // 8 MB; reused for P2
    unsigned short* P2     = (unsigned short*)(ws);                // alias (xbf dead by then)
    unsigned short* WxT    = (unsigned short*)(ws + 8388608);      // 4 MB
    unsigned short* WhT    = (unsigned short*)(ws + 12582912);     // 8 MB
    unsigned short* WattnT = (unsigned short*)(ws + 20971520);     // 8 MB
    unsigned short* Afl    = (unsigned short*)(ws + 29360128);     // 2 MB
    unsigned short* xwx2   = (unsigned short*)(ws + 31457280);     // 64 MB (swizzled)
    float* cstate          = (float*)(ws + 98566144);              // 256 KB
    ull* Ht                = (ull*)(ws + 98828288);                // 384 KB (2 slots tagged h)
    ull* wbuf_t            = (ull*)(ws + 99221504);                // 8 KB tagged w

    // no memsets needed: 0xAA poison never matches a valid tag

    k_cast_bf16<<<16384, 256, 0, stream>>>(x, xbf, 4194304);
    k_transpose_bf16<<<dim3(128, 16), 256, 0, stream>>>(Wx, WxT, 512);
    k_transpose_bf16<<<dim3(128, 32), 256, 0, stream>>>(Wh, WhT, 1024);
    k_transpose_bf16<<<dim3(128, 32), 256, 0, stream>>>(Wattn, WattnT, 1024);
    k_afl<<<4096, 256, 0, stream>>>(A, Afl);
    k_init<<<32, 256, 0, stream>>>(A, cstate, Ht);

    // xwx2 = swizzle(x@Wx + b) : M=8192, N=4096, K=512, mode 2
    k_gemm<<<dim3(32, 64), 256, 0, stream>>>(xbf, WxT, b, xwx2, 8192, 4096, 512, 2);
    // P2 = Afl@Wattn : M=1024, N=4096, K=1024, mode 1 (overwrites xbf region)
    k_gemm<<<dim3(32, 8), 256, 0, stream>>>(Afl, WattnT, nullptr, P2, 1024, 4096, 1024, 1);

    k_recur<<<272, 256, 0, stream>>>(A, WhT, xwx2, P2, cstate, Ht, wbuf_t, out);
}